// Round 3
// baseline (155.557 us; speedup 1.0000x reference)
//
#include <hip/hip_runtime.h>
#include <hip/hip_bf16.h>
#include <stdint.h>
#include <math.h>

#define N_ROWS 8192
#define DIM    512
#define BM     128
#define BK     64
#define NB     (N_ROWS / BM)          // 64 block-rows
#define NTRI   (NB * (NB + 1) / 2)    // 2080 triangle tiles
#define NXCD   8
#define CHUNK  (NTRI / NXCD)          // 260 tiles per XCD (exact)

typedef float  f32x4  __attribute__((ext_vector_type(4)));
typedef __bf16 bf16x8 __attribute__((ext_vector_type(8)));

__device__ __forceinline__ unsigned short f32_to_bf16_rne(float x) {
    unsigned u = __float_as_uint(x);
    u += 0x7fff + ((u >> 16) & 1);
    return (unsigned short)(u >> 16);
}

// ---- fused prep: normalize f -> bf16, posdot = f_hat . c_hat(label), zero S/K ----
__global__ __launch_bounds__(256) void k_prep(const float* __restrict__ feats,
                                              const float* __restrict__ centers,
                                              const int* __restrict__ labels,
                                              unsigned short* __restrict__ f_bf,
                                              float* __restrict__ posdot,
                                              float* __restrict__ Ssum,
                                              int* __restrict__ Kcnt) {
    const int row = blockIdx.x;
    const int t = threadIdx.x;
    const float* src = feats + (size_t)row * DIM;
    float v0 = src[t], v1 = src[t + 256];
    float ss = v0 * v0 + v1 * v1;
#pragma unroll
    for (int m = 1; m < 64; m <<= 1) ss += __shfl_xor(ss, m, 64);
    __shared__ float red[12];
    const int lane = t & 63, wid = t >> 6;
    if (lane == 0) red[wid] = ss;
    __syncthreads();
    const float tot = red[0] + red[1] + red[2] + red[3];
    const float scale = 1.0f / fmaxf(sqrtf(tot), 1e-12f);
    const float n0 = v0 * scale, n1 = v1 * scale;
    f_bf[(size_t)row * DIM + t]       = f32_to_bf16_rne(n0);
    f_bf[(size_t)row * DIM + t + 256] = f32_to_bf16_rne(n1);

    const int lab = labels[row];
    const float* c = centers + (size_t)lab * DIM;
    const float c0 = c[t], c1 = c[t + 256];
    float cc = c0 * c0 + c1 * c1;
    float d  = n0 * c0 + n1 * c1;
#pragma unroll
    for (int m = 1; m < 64; m <<= 1) {
        cc += __shfl_xor(cc, m, 64);
        d  += __shfl_xor(d, m, 64);
    }
    if (lane == 0) { red[4 + wid] = cc; red[8 + wid] = d; }
    __syncthreads();
    if (t == 0) {
        const float ctot = red[4] + red[5] + red[6] + red[7];
        const float dtot = red[8] + red[9] + red[10] + red[11];
        posdot[row] = dtot / fmaxf(sqrtf(ctot), 1e-12f);
        Ssum[row] = 0.0f;
        Kcnt[row] = 0;
    }
}

// ---------------- fused triangular A*A^T GEMM + masked row/col reduction ------
// Tile order: 8x8 supertiles of 8x8 tiles, supertile rows SI-major; bijective
// XCD chunk swizzle L = (b&7)*260 + (b>>3) gives each XCD a contiguous logical
// range -> per-XCD L2 working set ~= 8 A-panels + 8-16 B-panels (~2-3 MB).
__global__ __launch_bounds__(256) void k_pair(const unsigned short* __restrict__ f_bf,
                                              const int* __restrict__ labels,
                                              const float* __restrict__ pd,
                                              float* __restrict__ Ssum,
                                              int* __restrict__ Kcnt) {
    __shared__ __align__(16) unsigned char sA[BM * BK * 2];
    __shared__ __align__(16) unsigned char sB[BM * BK * 2];
    __shared__ int   s_lr[BM];
    __shared__ int   s_lc[BM];
    __shared__ float s_pd[BM];
    __shared__ float s_pc[BM];

    const int tid  = threadIdx.x;
    const int lane = tid & 63;
    const int wid  = tid >> 6;
    const int wr   = wid >> 1, wc = wid & 1;

    // --- XCD chunk swizzle + supertile decode ---
    const int L = (blockIdx.x & 7) * CHUNK + (blockIdx.x >> 3);
    int SI = 0, base = 0;
#pragma unroll
    for (int s = 0; s < 8; ++s) {
        const int rowlen = 36 + 64 * (7 - s);
        if (L >= base + rowlen) { base += rowlen; SI = s + 1; }
    }
    const int r0 = L - base;
    int bi, bj;
    if (r0 < 36) {                       // diagonal supertile: triangular walk
        int u = r0, ti = 0;
        while (u >= 8 - ti) { u -= 8 - ti; ++ti; }
        bi = SI * 8 + ti;
        bj = SI * 8 + ti + u;
    } else {
        const int q = r0 - 36;
        const int SJ = SI + 1 + q / 64;
        const int u = q % 64;
        bi = SI * 8 + u / 8;
        bj = SJ * 8 + u % 8;
    }
    const int rowBase = bi * BM;
    const int colBase = bj * BM;
    const bool offdiag = (bi != bj);

    if (tid < BM) {
        s_lr[tid] = labels[rowBase + tid];
        s_pd[tid] = pd[rowBase + tid];
    } else {
        s_lc[tid - BM] = labels[colBase + tid - BM];
        s_pc[tid - BM] = pd[colBase + tid - BM];
    }

    f32x4 acc[4][4] = {};

    // staging: each wave stages 4 chunks of 1KB per operand.
    const int srow = lane >> 3;
    const int sc16 = (lane & 7) ^ srow;

    for (int kt = 0; kt < DIM / BK; ++kt) {
        const int k0 = kt * BK;
        __syncthreads();
#pragma unroll
        for (int i = 0; i < 4; ++i) {
            const int ch = wid * 4 + i;
            const int r  = ch * 8 + srow;
            const unsigned short* gA = f_bf + ((size_t)(rowBase + r) * DIM + k0 + sc16 * 8);
            const unsigned short* gB = f_bf + ((size_t)(colBase + r) * DIM + k0 + sc16 * 8);
            __builtin_amdgcn_global_load_lds(
                (const __attribute__((address_space(1))) void*)gA,
                (__attribute__((address_space(3))) void*)(sA + ch * 1024), 16, 0, 0);
            __builtin_amdgcn_global_load_lds(
                (const __attribute__((address_space(1))) void*)gB,
                (__attribute__((address_space(3))) void*)(sB + ch * 1024), 16, 0, 0);
        }
        __syncthreads();

#pragma unroll
        for (int kk = 0; kk < 2; ++kk) {
            bf16x8 aF[4], bF[4];
#pragma unroll
            for (int m = 0; m < 4; ++m) {
                const int r = wr * 64 + m * 16 + (lane & 15);
                const int c16 = (kk * 4 + (lane >> 4)) ^ (r & 7);
                aF[m] = *(const bf16x8*)(sA + r * 128 + c16 * 16);
            }
#pragma unroll
            for (int n = 0; n < 4; ++n) {
                const int r = wc * 64 + n * 16 + (lane & 15);
                const int c16 = (kk * 4 + (lane >> 4)) ^ (r & 7);
                bF[n] = *(const bf16x8*)(sB + r * 128 + c16 * 16);
            }
#pragma unroll
            for (int m = 0; m < 4; ++m)
#pragma unroll
                for (int n = 0; n < 4; ++n)
                    acc[m][n] = __builtin_amdgcn_mfma_f32_16x16x32_bf16(aF[m], bF[n], acc[m][n], 0, 0, 0);
        }
    }

    // ---- masked row + column reduction epilogue ----
    // C/D layout: col = lane&15, row = (lane>>4)*4 + g (per 16x16 fragment)
    float colS[4] = {0.f, 0.f, 0.f, 0.f};
    int   colK[4] = {0, 0, 0, 0};
    int   lcv[4]; float pcv[4];
#pragma unroll
    for (int n = 0; n < 4; ++n) {
        const int jl = wc * 64 + n * 16 + (lane & 15);
        lcv[n] = s_lc[jl];
        pcv[n] = s_pc[jl];
    }

#pragma unroll
    for (int m = 0; m < 4; ++m) {
        float rowS[4] = {0.f, 0.f, 0.f, 0.f};
        int   rowK[4] = {0, 0, 0, 0};
        const int rbase = wr * 64 + m * 16 + ((lane >> 4) << 2);
        int myLr[4]; float myPd[4];
#pragma unroll
        for (int g = 0; g < 4; ++g) { myLr[g] = s_lr[rbase + g]; myPd[g] = s_pd[rbase + g]; }
#pragma unroll
        for (int n = 0; n < 4; ++n) {
#pragma unroll
            for (int g = 0; g < 4; ++g) {
                const float s = acc[m][n][g];
                const bool diff = (myLr[g] != lcv[n]);
                if (diff && s > myPd[g]) { rowS[g] += (s - myPd[g]); rowK[g] += 1; }
                if (offdiag && diff && s > pcv[n]) { colS[n] += (s - pcv[n]); colK[n] += 1; }
            }
        }
#pragma unroll
        for (int g = 0; g < 4; ++g) {
#pragma unroll
            for (int d = 1; d < 16; d <<= 1) {
                rowS[g] += __shfl_xor(rowS[g], d, 64);
                rowK[g] += __shfl_xor(rowK[g], d, 64);
            }
        }
        if ((lane & 15) == 0) {
#pragma unroll
            for (int g = 0; g < 4; ++g) {
                const int r = rowBase + rbase + g;
                atomicAdd(&Ssum[r], rowS[g]);
                atomicAdd(&Kcnt[r], rowK[g]);
            }
        }
    }

    if (offdiag) {
#pragma unroll
        for (int n = 0; n < 4; ++n) {
#pragma unroll
            for (int d = 16; d < 64; d <<= 1) {
                colS[n] += __shfl_xor(colS[n], d, 64);
                colK[n] += __shfl_xor(colK[n], d, 64);
            }
        }
        if (lane < 16) {
#pragma unroll
            for (int n = 0; n < 4; ++n) {
                const int c = colBase + wc * 64 + n * 16 + lane;
                atomicAdd(&Ssum[c], colS[n]);
                atomicAdd(&Kcnt[c], colK[n]);
            }
        }
    }
}

// ---------------- final scalar reduction ----------------
__global__ __launch_bounds__(1024) void k_final(const float* __restrict__ Ssum,
                                                const int* __restrict__ Kcnt,
                                                float* __restrict__ out) {
    const int t = threadIdx.x;
    double sum = 0.0; int cnt = 0;
    for (int i = t; i < N_ROWS; i += 1024) {
        const int k = Kcnt[i];
        if (k > 0) { sum += (double)Ssum[i] / (double)k; cnt += 1; }
    }
#pragma unroll
    for (int d = 1; d < 64; d <<= 1) {
        sum += __shfl_xor(sum, d, 64);
        cnt += __shfl_xor(cnt, d, 64);
    }
    __shared__ double s_sum[16];
    __shared__ int    s_cnt[16];
    const int lane = t & 63, wid = t >> 6;
    if (lane == 0) { s_sum[wid] = sum; s_cnt[wid] = cnt; }
    __syncthreads();
    if (t == 0) {
        double ts = 0.0; int tc = 0;
#pragma unroll
        for (int w = 0; w < 16; ++w) { ts += s_sum[w]; tc += s_cnt[w]; }
        out[0] = (float)(tc > 0 ? ts / (double)tc : ts);
    }
}

extern "C" void kernel_launch(void* const* d_in, const int* in_sizes, int n_in,
                              void* d_out, int out_size, void* d_ws, size_t ws_size,
                              hipStream_t stream) {
    const float* features = (const float*)d_in[0];
    const float* centers  = (const float*)d_in[1];
    const int*   labels   = (const int*)d_in[2];
    float* out = (float*)d_out;

    char* ws = (char*)d_ws;
    unsigned short* f_bf   = (unsigned short*)(ws);               // 8,388,608 B
    float*          posdot = (float*)(ws + 0x800000);             // 32,768 B
    float*          Ssum   = (float*)(ws + 0x800000 + 0x8000);
    int*            Kcnt   = (int*)  (ws + 0x800000 + 0x10000);

    k_prep<<<N_ROWS, 256, 0, stream>>>(features, centers, labels, f_bf, posdot, Ssum, Kcnt);
    k_pair<<<NTRI, 256, 0, stream>>>(f_bf, labels, posdot, Ssum, Kcnt);
    k_final<<<1, 1024, 0, stream>>>(Ssum, Kcnt, out);
}

// Round 4
// 127.746 us; speedup vs baseline: 1.2177x; 1.2177x over previous
//
#include <hip/hip_runtime.h>
#include <hip/hip_bf16.h>
#include <stdint.h>
#include <math.h>

#define N_ROWS 8192
#define DIM    512
#define BM     128
#define BK     64
#define NB     (N_ROWS / BM)          // 64 block-rows
#define NTRI   (NB * (NB + 1) / 2)    // 2080 triangle tiles
#define NKT    (DIM / BK)             // 8 K-steps

typedef float  f32x4  __attribute__((ext_vector_type(4)));
typedef __bf16 bf16x8 __attribute__((ext_vector_type(8)));

__device__ __forceinline__ unsigned short f32_to_bf16_rne(float x) {
    unsigned u = __float_as_uint(x);
    u += 0x7fff + ((u >> 16) & 1);
    return (unsigned short)(u >> 16);
}

// ---- fused prep: normalize f -> bf16, posdot = f_hat . c_hat(label), zero S/K ----
__global__ __launch_bounds__(256) void k_prep(const float* __restrict__ feats,
                                              const float* __restrict__ centers,
                                              const int* __restrict__ labels,
                                              unsigned short* __restrict__ f_bf,
                                              float* __restrict__ posdot,
                                              float* __restrict__ Ssum,
                                              int* __restrict__ Kcnt) {
    const int row = blockIdx.x;
    const int t = threadIdx.x;
    const float* src = feats + (size_t)row * DIM;
    float v0 = src[t], v1 = src[t + 256];
    float ss = v0 * v0 + v1 * v1;
#pragma unroll
    for (int m = 1; m < 64; m <<= 1) ss += __shfl_xor(ss, m, 64);
    __shared__ float red[12];
    const int lane = t & 63, wid = t >> 6;
    if (lane == 0) red[wid] = ss;
    __syncthreads();
    const float tot = red[0] + red[1] + red[2] + red[3];
    const float scale = 1.0f / fmaxf(sqrtf(tot), 1e-12f);
    const float n0 = v0 * scale, n1 = v1 * scale;
    f_bf[(size_t)row * DIM + t]       = f32_to_bf16_rne(n0);
    f_bf[(size_t)row * DIM + t + 256] = f32_to_bf16_rne(n1);

    const int lab = labels[row];
    const float* c = centers + (size_t)lab * DIM;
    const float c0 = c[t], c1 = c[t + 256];
    float cc = c0 * c0 + c1 * c1;
    float d  = n0 * c0 + n1 * c1;
#pragma unroll
    for (int m = 1; m < 64; m <<= 1) {
        cc += __shfl_xor(cc, m, 64);
        d  += __shfl_xor(d, m, 64);
    }
    if (lane == 0) { red[4 + wid] = cc; red[8 + wid] = d; }
    __syncthreads();
    if (t == 0) {
        const float ctot = red[4] + red[5] + red[6] + red[7];
        const float dtot = red[8] + red[9] + red[10] + red[11];
        posdot[row] = dtot / fmaxf(sqrtf(ctot), 1e-12f);
        Ssum[row] = 0.0f;
        Kcnt[row] = 0;
    }
}

// ---------------- fused triangular A*A^T GEMM + masked row/col reduction ------
// 2-phase double-buffered K-loop (T3-minimal): issue global_load_lds for tile
// k+1 into the spare buffer, compute tile k, then ONE __syncthreads() whose
// implicit vmcnt(0)/lgkmcnt(0) drain publishes the prefetch. Load latency
// hides under the 32 MFMA + 16 ds_read of the current step.
// LDS st-swizzled: phys(r,c16) = r*128 + ((c16 ^ (r&7))*16) bytes; the
// global_load_lds SOURCE carries the inverse swizzle (linear LDS dest).
__global__ __launch_bounds__(256) void k_pair(const unsigned short* __restrict__ f_bf,
                                              const int* __restrict__ labels,
                                              const float* __restrict__ pd,
                                              float* __restrict__ Ssum,
                                              int* __restrict__ Kcnt) {
    __shared__ __align__(16) unsigned char sA[2][BM * BK * 2];
    __shared__ __align__(16) unsigned char sB[2][BM * BK * 2];
    __shared__ int   s_lr[BM];
    __shared__ int   s_lc[BM];
    __shared__ float s_pd[BM];
    __shared__ float s_pc[BM];

    const int tid  = threadIdx.x;
    const int lane = tid & 63;
    const int wid  = tid >> 6;
    const int wr   = wid >> 1, wc = wid & 1;

    // triangle index -> (bi, bj), bi <= bj  (raw linearization; R2-proven)
    const int t = blockIdx.x;
    int bi = (int)floor((2.0 * NB + 1.0 - sqrt((2.0 * NB + 1.0) * (2.0 * NB + 1.0) - 8.0 * (double)t)) * 0.5);
    while (bi * NB - bi * (bi - 1) / 2 > t) --bi;
    while ((bi + 1) * NB - (bi + 1) * bi / 2 <= t) ++bi;
    const int bj = bi + (t - (bi * NB - bi * (bi - 1) / 2));
    const int rowBase = bi * BM;
    const int colBase = bj * BM;
    const bool offdiag = (bi != bj);

    if (tid < BM) {
        s_lr[tid] = labels[rowBase + tid];
        s_pd[tid] = pd[rowBase + tid];
    } else {
        s_lc[tid - BM] = labels[colBase + tid - BM];
        s_pc[tid - BM] = pd[colBase + tid - BM];
    }

    f32x4 acc[4][4] = {};

    // staging: each wave stages 4 chunks of 1KB per operand per K-step.
    // chunk ch covers rows ch*8..ch*8+7; lane -> (row = ch*8+lane>>3, fetch col16 = (lane&7)^row7)
    const int srow = lane >> 3;
    const int sc16 = (lane & 7) ^ srow;

#define STAGE(KT, P)                                                                       \
    do {                                                                                   \
        const int k0_ = (KT) * BK;                                                         \
        _Pragma("unroll")                                                                  \
        for (int i_ = 0; i_ < 4; ++i_) {                                                   \
            const int ch_ = wid * 4 + i_;                                                  \
            const int r_  = ch_ * 8 + srow;                                                \
            const unsigned short* gA_ = f_bf + ((size_t)(rowBase + r_) * DIM + k0_ + sc16 * 8); \
            const unsigned short* gB_ = f_bf + ((size_t)(colBase + r_) * DIM + k0_ + sc16 * 8); \
            __builtin_amdgcn_global_load_lds(                                              \
                (const __attribute__((address_space(1))) void*)gA_,                        \
                (__attribute__((address_space(3))) void*)(&sA[P][ch_ * 1024]), 16, 0, 0);  \
            __builtin_amdgcn_global_load_lds(                                              \
                (const __attribute__((address_space(1))) void*)gB_,                        \
                (__attribute__((address_space(3))) void*)(&sB[P][ch_ * 1024]), 16, 0, 0);  \
        }                                                                                  \
    } while (0)

#define COMPUTE(P)                                                                         \
    do {                                                                                   \
        _Pragma("unroll")                                                                  \
        for (int kk = 0; kk < 2; ++kk) {                                                   \
            bf16x8 aF[4], bF[4];                                                           \
            _Pragma("unroll")                                                              \
            for (int m = 0; m < 4; ++m) {                                                  \
                const int r = wr * 64 + m * 16 + (lane & 15);                              \
                const int c16 = (kk * 4 + (lane >> 4)) ^ (r & 7);                          \
                aF[m] = *(const bf16x8*)(&sA[P][r * 128 + c16 * 16]);                      \
            }                                                                              \
            _Pragma("unroll")                                                              \
            for (int n = 0; n < 4; ++n) {                                                  \
                const int r = wc * 64 + n * 16 + (lane & 15);                              \
                const int c16 = (kk * 4 + (lane >> 4)) ^ (r & 7);                          \
                bF[n] = *(const bf16x8*)(&sB[P][r * 128 + c16 * 16]);                      \
            }                                                                              \
            _Pragma("unroll")                                                              \
            for (int m = 0; m < 4; ++m)                                                    \
                _Pragma("unroll")                                                          \
                for (int n = 0; n < 4; ++n)                                                \
                    acc[m][n] = __builtin_amdgcn_mfma_f32_16x16x32_bf16(aF[m], bF[n], acc[m][n], 0, 0, 0); \
        }                                                                                  \
    } while (0)

    STAGE(0, 0);
    __syncthreads();   // drains stage(0) + publishes s_lr/s_pd/s_lc/s_pc

    for (int kt = 0; kt < NKT - 1; ++kt) {
        const int cur = kt & 1;
        STAGE(kt + 1, cur ^ 1);   // prefetch next tile into spare buffer
        COMPUTE(cur);             // MFMA current tile (hides load latency)
        __syncthreads();          // implicit vmcnt(0): prefetch landed; buf cur free
    }
    COMPUTE((NKT - 1) & 1);

#undef STAGE
#undef COMPUTE

    // ---- masked row + column reduction epilogue ----
    // C/D layout: col = lane&15, row = (lane>>4)*4 + g (per 16x16 fragment)
    float colS[4] = {0.f, 0.f, 0.f, 0.f};
    int   colK[4] = {0, 0, 0, 0};
    int   lcv[4]; float pcv[4];
#pragma unroll
    for (int n = 0; n < 4; ++n) {
        const int jl = wc * 64 + n * 16 + (lane & 15);
        lcv[n] = s_lc[jl];
        pcv[n] = s_pc[jl];
    }

#pragma unroll
    for (int m = 0; m < 4; ++m) {
        float rowS[4] = {0.f, 0.f, 0.f, 0.f};
        int   rowK[4] = {0, 0, 0, 0};
        const int rbase = wr * 64 + m * 16 + ((lane >> 4) << 2);
        int myLr[4]; float myPd[4];
#pragma unroll
        for (int g = 0; g < 4; ++g) { myLr[g] = s_lr[rbase + g]; myPd[g] = s_pd[rbase + g]; }
#pragma unroll
        for (int n = 0; n < 4; ++n) {
#pragma unroll
            for (int g = 0; g < 4; ++g) {
                const float s = acc[m][n][g];
                const bool diff = (myLr[g] != lcv[n]);
                if (diff && s > myPd[g]) { rowS[g] += (s - myPd[g]); rowK[g] += 1; }
                if (offdiag && diff && s > pcv[n]) { colS[n] += (s - pcv[n]); colK[n] += 1; }
            }
        }
#pragma unroll
        for (int g = 0; g < 4; ++g) {
#pragma unroll
            for (int d = 1; d < 16; d <<= 1) {
                rowS[g] += __shfl_xor(rowS[g], d, 64);
                rowK[g] += __shfl_xor(rowK[g], d, 64);
            }
        }
        if ((lane & 15) == 0) {
#pragma unroll
            for (int g = 0; g < 4; ++g) {
                const int r = rowBase + rbase + g;
                atomicAdd(&Ssum[r], rowS[g]);
                atomicAdd(&Kcnt[r], rowK[g]);
            }
        }
    }

    if (offdiag) {
#pragma unroll
        for (int n = 0; n < 4; ++n) {
#pragma unroll
            for (int d = 16; d < 64; d <<= 1) {
                colS[n] += __shfl_xor(colS[n], d, 64);
                colK[n] += __shfl_xor(colK[n], d, 64);
            }
        }
        if (lane < 16) {
#pragma unroll
            for (int n = 0; n < 4; ++n) {
                const int c = colBase + wc * 64 + n * 16 + lane;
                atomicAdd(&Ssum[c], colS[n]);
                atomicAdd(&Kcnt[c], colK[n]);
            }
        }
    }
}

// ---------------- final scalar reduction ----------------
__global__ __launch_bounds__(1024) void k_final(const float* __restrict__ Ssum,
                                                const int* __restrict__ Kcnt,
                                                float* __restrict__ out) {
    const int t = threadIdx.x;
    double sum = 0.0; int cnt = 0;
    for (int i = t; i < N_ROWS; i += 1024) {
        const int k = Kcnt[i];
        if (k > 0) { sum += (double)Ssum[i] / (double)k; cnt += 1; }
    }
#pragma unroll
    for (int d = 1; d < 64; d <<= 1) {
        sum += __shfl_xor(sum, d, 64);
        cnt += __shfl_xor(cnt, d, 64);
    }
    __shared__ double s_sum[16];
    __shared__ int    s_cnt[16];
    const int lane = t & 63, wid = t >> 6;
    if (lane == 0) { s_sum[wid] = sum; s_cnt[wid] = cnt; }
    __syncthreads();
    if (t == 0) {
        double ts = 0.0; int tc = 0;
#pragma unroll
        for (int w = 0; w < 16; ++w) { ts += s_sum[w]; tc += s_cnt[w]; }
        out[0] = (float)(tc > 0 ? ts / (double)tc : ts);
    }
}

extern "C" void kernel_launch(void* const* d_in, const int* in_sizes, int n_in,
                              void* d_out, int out_size, void* d_ws, size_t ws_size,
                              hipStream_t stream) {
    const float* features = (const float*)d_in[0];
    const float* centers  = (const float*)d_in[1];
    const int*   labels   = (const int*)d_in[2];
    float* out = (float*)d_out;

    char* ws = (char*)d_ws;
    unsigned short* f_bf   = (unsigned short*)(ws);               // 8,388,608 B
    float*          posdot = (float*)(ws + 0x800000);             // 32,768 B
    float*          Ssum   = (float*)(ws + 0x800000 + 0x8000);
    int*            Kcnt   = (int*)  (ws + 0x800000 + 0x10000);

    k_prep<<<N_ROWS, 256, 0, stream>>>(features, centers, labels, f_bf, posdot, Ssum, Kcnt);
    k_pair<<<NTRI, 256, 0, stream>>>(f_bf, labels, posdot, Ssum, Kcnt);
    k_final<<<1, 1024, 0, stream>>>(Ssum, Kcnt, out);
}

// Round 5
// 90.091 us; speedup vs baseline: 1.7267x; 1.4180x over previous
//
#include <hip/hip_runtime.h>
#include <hip/hip_bf16.h>
#include <hip/hip_fp8.h>
#include <stdint.h>
#include <math.h>

#define N_ROWS 8192
#define DIM    512
#define BM     128
#define BK     64
#define NB     (N_ROWS / BM)          // 64 block-rows
#define NTRI   (NB * (NB + 1) / 2)    // 2080 triangle tiles
#define NKT    (DIM / BK)             // 8 K-steps

typedef float f32x4 __attribute__((ext_vector_type(4)));

// ---- fused prep: normalize f -> fp8 e4m3, posdot = f_hat . c_hat(label), zero S/K ----
__global__ __launch_bounds__(256) void k_prep(const float* __restrict__ feats,
                                              const float* __restrict__ centers,
                                              const int* __restrict__ labels,
                                              unsigned char* __restrict__ f_q,
                                              float* __restrict__ posdot,
                                              float* __restrict__ Ssum,
                                              int* __restrict__ Kcnt) {
    const int row = blockIdx.x;
    const int t = threadIdx.x;
    const float* src = feats + (size_t)row * DIM;
    float v0 = src[t], v1 = src[t + 256];
    float ss = v0 * v0 + v1 * v1;
#pragma unroll
    for (int m = 1; m < 64; m <<= 1) ss += __shfl_xor(ss, m, 64);
    __shared__ float red[12];
    const int lane = t & 63, wid = t >> 6;
    if (lane == 0) red[wid] = ss;
    __syncthreads();
    const float tot = red[0] + red[1] + red[2] + red[3];
    const float scale = 1.0f / fmaxf(sqrtf(tot), 1e-12f);
    const float n0 = v0 * scale, n1 = v1 * scale;
    {
        __hip_fp8_e4m3 q0(n0), q1(n1);
        f_q[(size_t)row * DIM + t]       = *reinterpret_cast<const unsigned char*>(&q0);
        f_q[(size_t)row * DIM + t + 256] = *reinterpret_cast<const unsigned char*>(&q1);
    }

    const int lab = labels[row];
    const float* c = centers + (size_t)lab * DIM;
    const float c0 = c[t], c1 = c[t + 256];
    float cc = c0 * c0 + c1 * c1;
    float d  = n0 * c0 + n1 * c1;
#pragma unroll
    for (int m = 1; m < 64; m <<= 1) {
        cc += __shfl_xor(cc, m, 64);
        d  += __shfl_xor(d, m, 64);
    }
    if (lane == 0) { red[4 + wid] = cc; red[8 + wid] = d; }
    __syncthreads();
    if (t == 0) {
        const float ctot = red[4] + red[5] + red[6] + red[7];
        const float dtot = red[8] + red[9] + red[10] + red[11];
        posdot[row] = dtot / fmaxf(sqrtf(ctot), 1e-12f);
        Ssum[row] = 0.0f;
        Kcnt[row] = 0;
    }
}

// ---------------- fused triangular A*A^T fp8 GEMM + masked row/col reduction ---
// 2-phase double-buffered K-loop; fp8 tiles are 8KB/operand/step -> 32KB dbuf
// -> 4 blocks/CU (TLP) on top of the 1-deep prefetch (ILP).
// LDS swizzle at 16B granularity: phys c16 = c16 ^ ((r>>1)&3). The
// global_load_lds SOURCE carries the inverse (same) permutation; b64 fragment
// reads are bank-balanced (4 words/bank = b64 floor).
__global__ __launch_bounds__(256) void k_pair(const unsigned char* __restrict__ f_q,
                                              const int* __restrict__ labels,
                                              const float* __restrict__ pd,
                                              float* __restrict__ Ssum,
                                              int* __restrict__ Kcnt) {
    __shared__ __align__(16) unsigned char sA[2][BM * BK];
    __shared__ __align__(16) unsigned char sB[2][BM * BK];
    __shared__ int   s_lr[BM];
    __shared__ int   s_lc[BM];
    __shared__ float s_pd[BM];
    __shared__ float s_pc[BM];

    const int tid  = threadIdx.x;
    const int lane = tid & 63;
    const int wid  = tid >> 6;
    const int wr   = wid >> 1, wc = wid & 1;

    // triangle index -> (bi, bj), bi <= bj
    const int t = blockIdx.x;
    int bi = (int)floor((2.0 * NB + 1.0 - sqrt((2.0 * NB + 1.0) * (2.0 * NB + 1.0) - 8.0 * (double)t)) * 0.5);
    while (bi * NB - bi * (bi - 1) / 2 > t) --bi;
    while ((bi + 1) * NB - (bi + 1) * bi / 2 <= t) ++bi;
    const int bj = bi + (t - (bi * NB - bi * (bi - 1) / 2));
    const int rowBase = bi * BM;
    const int colBase = bj * BM;
    const bool offdiag = (bi != bj);

    if (tid < BM) {
        s_lr[tid] = labels[rowBase + tid];
        s_pd[tid] = pd[rowBase + tid];
    } else {
        s_lc[tid - BM] = labels[colBase + tid - BM];
        s_pc[tid - BM] = pd[colBase + tid - BM];
    }

    f32x4 acc[4][4] = {};

    // staging: 8 chunks of 1KB per operand per K-step; 2 chunks/wave/operand.
    // chunk ch covers rows ch*16..ch*16+15; lane -> row = ch*16 + (lane>>2),
    // source col16 = (lane&3) ^ ((lane>>3)&3)  (inverse of the read swizzle).
    const int srow  = lane >> 2;
    const int sc16  = (lane & 3) ^ ((lane >> 3) & 3);

#define STAGE(KT, P)                                                                       \
    do {                                                                                   \
        const int k0_ = (KT) * BK;                                                         \
        _Pragma("unroll")                                                                  \
        for (int i_ = 0; i_ < 2; ++i_) {                                                   \
            const int ch_ = wid * 2 + i_;                                                  \
            const int r_  = ch_ * 16 + srow;                                               \
            const unsigned char* gA_ = f_q + ((size_t)(rowBase + r_) * DIM + k0_ + sc16 * 16); \
            const unsigned char* gB_ = f_q + ((size_t)(colBase + r_) * DIM + k0_ + sc16 * 16); \
            __builtin_amdgcn_global_load_lds(                                              \
                (const __attribute__((address_space(1))) void*)gA_,                        \
                (__attribute__((address_space(3))) void*)(&sA[P][ch_ * 1024]), 16, 0, 0);  \
            __builtin_amdgcn_global_load_lds(                                              \
                (const __attribute__((address_space(1))) void*)gB_,                        \
                (__attribute__((address_space(3))) void*)(&sB[P][ch_ * 1024]), 16, 0, 0);  \
        }                                                                                  \
    } while (0)

#define COMPUTE(P)                                                                         \
    do {                                                                                   \
        _Pragma("unroll")                                                                  \
        for (int kk = 0; kk < 2; ++kk) {                                                   \
            long aF[4], bF[4];                                                             \
            const int c8 = kk * 4 + (lane >> 4);                                           \
            _Pragma("unroll")                                                              \
            for (int m = 0; m < 4; ++m) {                                                  \
                const int r = wr * 64 + m * 16 + (lane & 15);                              \
                const int c16p = (c8 >> 1) ^ ((r >> 1) & 3);                               \
                aF[m] = *(const long*)(&sA[P][r * 64 + c16p * 16 + (c8 & 1) * 8]);         \
            }                                                                              \
            _Pragma("unroll")                                                              \
            for (int n = 0; n < 4; ++n) {                                                  \
                const int r = wc * 64 + n * 16 + (lane & 15);                              \
                const int c16p = (c8 >> 1) ^ ((r >> 1) & 3);                               \
                bF[n] = *(const long*)(&sB[P][r * 64 + c16p * 16 + (c8 & 1) * 8]);         \
            }                                                                              \
            _Pragma("unroll")                                                              \
            for (int m = 0; m < 4; ++m)                                                    \
                _Pragma("unroll")                                                          \
                for (int n = 0; n < 4; ++n)                                                \
                    acc[m][n] = __builtin_amdgcn_mfma_f32_16x16x32_fp8_fp8(aF[m], bF[n], acc[m][n], 0, 0, 0); \
        }                                                                                  \
    } while (0)

    STAGE(0, 0);
    __syncthreads();   // drains stage(0) + publishes s_lr/s_pd/s_lc/s_pc

    for (int kt = 0; kt < NKT - 1; ++kt) {
        const int cur = kt & 1;
        STAGE(kt + 1, cur ^ 1);   // prefetch next tile into spare buffer
        COMPUTE(cur);             // MFMA current tile (hides load latency)
        __syncthreads();          // implicit vmcnt(0): prefetch landed; buf cur free
    }
    COMPUTE((NKT - 1) & 1);

#undef STAGE
#undef COMPUTE

    // ---- masked row + column reduction epilogue ----
    // C/D layout: col = lane&15, row = (lane>>4)*4 + g (per 16x16 fragment)
    float colS[4] = {0.f, 0.f, 0.f, 0.f};
    int   colK[4] = {0, 0, 0, 0};
    int   lcv[4]; float pcv[4];
#pragma unroll
    for (int n = 0; n < 4; ++n) {
        const int jl = wc * 64 + n * 16 + (lane & 15);
        lcv[n] = s_lc[jl];
        pcv[n] = s_pc[jl];
    }

#pragma unroll
    for (int m = 0; m < 4; ++m) {
        float rowS[4] = {0.f, 0.f, 0.f, 0.f};
        int   rowK[4] = {0, 0, 0, 0};
        const int rbase = wr * 64 + m * 16 + ((lane >> 4) << 2);
        int myLr[4]; float myPd[4];
#pragma unroll
        for (int g = 0; g < 4; ++g) { myLr[g] = s_lr[rbase + g]; myPd[g] = s_pd[rbase + g]; }
#pragma unroll
        for (int n = 0; n < 4; ++n) {
#pragma unroll
            for (int g = 0; g < 4; ++g) {
                const float s = acc[m][n][g];
                const bool diff = (myLr[g] != lcv[n]);
                if (diff && s > myPd[g]) { rowS[g] += (s - myPd[g]); rowK[g] += 1; }
                if (offdiag && diff && s > pcv[n]) { colS[n] += (s - pcv[n]); colK[n] += 1; }
            }
        }
#pragma unroll
        for (int g = 0; g < 4; ++g) {
#pragma unroll
            for (int d = 1; d < 16; d <<= 1) {
                rowS[g] += __shfl_xor(rowS[g], d, 64);
                rowK[g] += __shfl_xor(rowK[g], d, 64);
            }
        }
        if ((lane & 15) == 0) {
#pragma unroll
            for (int g = 0; g < 4; ++g) {
                const int r = rowBase + rbase + g;
                atomicAdd(&Ssum[r], rowS[g]);
                atomicAdd(&Kcnt[r], rowK[g]);
            }
        }
    }

    if (offdiag) {
#pragma unroll
        for (int n = 0; n < 4; ++n) {
#pragma unroll
            for (int d = 16; d < 64; d <<= 1) {
                colS[n] += __shfl_xor(colS[n], d, 64);
                colK[n] += __shfl_xor(colK[n], d, 64);
            }
        }
        if (lane < 16) {
#pragma unroll
            for (int n = 0; n < 4; ++n) {
                const int c = colBase + wc * 64 + n * 16 + lane;
                atomicAdd(&Ssum[c], colS[n]);
                atomicAdd(&Kcnt[c], colK[n]);
            }
        }
    }
}

// ---------------- final scalar reduction ----------------
__global__ __launch_bounds__(1024) void k_final(const float* __restrict__ Ssum,
                                                const int* __restrict__ Kcnt,
                                                float* __restrict__ out) {
    const int t = threadIdx.x;
    double sum = 0.0; int cnt = 0;
    for (int i = t; i < N_ROWS; i += 1024) {
        const int k = Kcnt[i];
        if (k > 0) { sum += (double)Ssum[i] / (double)k; cnt += 1; }
    }
#pragma unroll
    for (int d = 1; d < 64; d <<= 1) {
        sum += __shfl_xor(sum, d, 64);
        cnt += __shfl_xor(cnt, d, 64);
    }
    __shared__ double s_sum[16];
    __shared__ int    s_cnt[16];
    const int lane = t & 63, wid = t >> 6;
    if (lane == 0) { s_sum[wid] = sum; s_cnt[wid] = cnt; }
    __syncthreads();
    if (t == 0) {
        double ts = 0.0; int tc = 0;
#pragma unroll
        for (int w = 0; w < 16; ++w) { ts += s_sum[w]; tc += s_cnt[w]; }
        out[0] = (float)(tc > 0 ? ts / (double)tc : ts);
    }
}

extern "C" void kernel_launch(void* const* d_in, const int* in_sizes, int n_in,
                              void* d_out, int out_size, void* d_ws, size_t ws_size,
                              hipStream_t stream) {
    const float* features = (const float*)d_in[0];
    const float* centers  = (const float*)d_in[1];
    const int*   labels   = (const int*)d_in[2];
    float* out = (float*)d_out;

    char* ws = (char*)d_ws;
    unsigned char* f_q    = (unsigned char*)(ws);                 // 4,194,304 B
    float*         posdot = (float*)(ws + 0x400000);              // 32,768 B
    float*         Ssum   = (float*)(ws + 0x400000 + 0x8000);
    int*           Kcnt   = (int*)  (ws + 0x400000 + 0x10000);

    k_prep<<<N_ROWS, 256, 0, stream>>>(features, centers, labels, f_q, posdot, Ssum, Kcnt);
    k_pair<<<NTRI, 256, 0, stream>>>(f_q, labels, posdot, Ssum, Kcnt);
    k_final<<<1, 1024, 0, stream>>>(Ssum, Kcnt, out);
}